// Round 3
// baseline (318.624 us; speedup 1.0000x reference)
//
#include <hip/hip_runtime.h>

#define N_NODES 100000
#define D_SRC 128
#define D_OUT 256
#define K_DIM 256   // D_DST + D_SRC
#define CAP 32      // bucket capacity per node (Poisson(6): P(deg>32) ~ 1e-15)
#define OVF_CAP 2048

typedef __attribute__((ext_vector_type(8))) short short8;
typedef __attribute__((ext_vector_type(4))) float float4v;

__device__ inline unsigned short f2bf(float f) {
    unsigned int u = __float_as_uint(f);
    u += 0x7FFF + ((u >> 16) & 1);   // round-to-nearest-even
    return (unsigned short)(u >> 16);
}
__device__ inline float bf_lo(unsigned int u) { return __uint_as_float(u << 16); }
__device__ inline float bf_hi(unsigned int u) { return __uint_as_float(u & 0xFFFF0000u); }

// ---------------------------------------------------------------------------
// Kernel 1 (fused prep): one launch does all independent elementwise work:
//   blocks [0, 12500)      : x_src fp32 -> bf16 linear pack (xsb)
//   blocks [12500, 18750)  : x_dst fp32 -> bf16 MFMA-fragment pack (xdsw)
//   blocks [18750, 18782)  : W fp32 -> bf16 MFMA-fragment pack (wsw)
//   blocks [18782, 18880)  : zero deg + ovf_cnt (int4 stores)
// Replaces 3 kernels + 1 hipMemsetAsync.
// ---------------------------------------------------------------------------
#define PREP_SRC_BLOCKS 12500              // N*128/4 float4 / 256
#define PREP_DST_BLOCKS 6250               // N*16 threads / 256
#define PREP_W_BLOCKS   32                 // 256*256/8 / 256
#define PREP_Z_BLOCKS   98                 // ceil((N+4)/4 int4 / 256)
#define PREP_BLOCKS (PREP_SRC_BLOCKS + PREP_DST_BLOCKS + PREP_W_BLOCKS + PREP_Z_BLOCKS)

__global__ __launch_bounds__(256) void prep_kernel(
    const float* __restrict__ x_src,
    const float* __restrict__ x_dst,
    const float* __restrict__ W,
    unsigned short* __restrict__ xsb,
    unsigned short* __restrict__ xdsw,
    unsigned short* __restrict__ wsw,
    int* __restrict__ deg)             // zeroes N_NODES+4 ints (deg + ovf_cnt)
{
    int b = blockIdx.x;
    if (b < PREP_SRC_BLOCKS) {
        // ---- pack_src: one float4 -> ushort4 per thread, grid exact ----
        int i = b * 256 + threadIdx.x;
        float4 v = ((const float4*)x_src)[i];
        ushort4 o;
        o.x = f2bf(v.x); o.y = f2bf(v.y); o.z = f2bf(v.z); o.w = f2bf(v.w);
        ((ushort4*)xsb)[i] = o;
    } else if (b < PREP_SRC_BLOCKS + PREP_DST_BLOCKS) {
        // ---- pack_dst fragment-order ----
        // granule ((r>>4)*4 + kc)*64 + (r&15) + 16*sub  <- x_dst[r][kc*32+sub*8+j]
        int t = (b - PREP_SRC_BLOCKS) * 256 + threadIdx.x;
        int r = t >> 4;
        int g = t & 15;
        const float4* p = (const float4*)(x_dst + (size_t)r * 128 + g * 8);
        float4 v0 = p[0], v1 = p[1];
        union { unsigned short s[8]; short8 v; } pk;
        pk.s[0] = f2bf(v0.x); pk.s[1] = f2bf(v0.y);
        pk.s[2] = f2bf(v0.z); pk.s[3] = f2bf(v0.w);
        pk.s[4] = f2bf(v1.x); pk.s[5] = f2bf(v1.y);
        pk.s[6] = f2bf(v1.z); pk.s[7] = f2bf(v1.w);
        size_t gr = ((size_t)(r >> 4) * 4 + (g >> 2)) * 64 + (r & 15) + ((g & 3) << 4);
        ((short8*)xdsw)[gr] = pk.v;
    } else if (b < PREP_SRC_BLOCKS + PREP_DST_BLOCKS + PREP_W_BLOCKS) {
        // ---- convert_w fragment-order ----
        // granule ((r>>4)*8 + kc)*64 + (r&15) + 16*sub  (r = out-row)
        int t = (b - PREP_SRC_BLOCKS - PREP_DST_BLOCKS) * 256 + threadIdx.x;
        int r = t >> 5;
        int g = t & 31;
        const float4* p = (const float4*)(W + (size_t)r * 256 + g * 8);
        float4 v0 = p[0], v1 = p[1];
        union { unsigned short s[8]; short8 v; } pk;
        pk.s[0] = f2bf(v0.x); pk.s[1] = f2bf(v0.y);
        pk.s[2] = f2bf(v0.z); pk.s[3] = f2bf(v0.w);
        pk.s[4] = f2bf(v1.x); pk.s[5] = f2bf(v1.y);
        pk.s[6] = f2bf(v1.z); pk.s[7] = f2bf(v1.w);
        size_t gr = ((size_t)(r >> 4) * 8 + (g >> 2)) * 64 + (r & 15) + ((g & 3) << 4);
        ((short8*)wsw)[gr] = pk.v;
    } else {
        // ---- zero deg + ovf_cnt: (N_NODES+4) ints = 25001 int4 exact ----
        int i = (b - PREP_SRC_BLOCKS - PREP_DST_BLOCKS - PREP_W_BLOCKS) * 256 + threadIdx.x;
        if (i < (N_NODES + 4) / 4)
            ((int4*)deg)[i] = make_int4(0, 0, 0, 0);
    }
}

// ---------------------------------------------------------------------------
// Kernel 2: bucket edges by dst. (unchanged)
// ---------------------------------------------------------------------------
__global__ __launch_bounds__(256) void bucket_kernel(
    const int* __restrict__ ei,     // [2, E]
    int* __restrict__ deg,          // [N] (pre-zeroed)
    int* __restrict__ ovf_cnt,      // [1] (pre-zeroed)
    int* __restrict__ ovf,          // [OVF_CAP*2]
    int* __restrict__ bucket,       // [N*CAP]
    int n_edges)
{
    int e = blockIdx.x * 256 + threadIdx.x;
    if (e >= n_edges) return;
    int s = ei[e];
    int d = ei[n_edges + e];
    int pos = atomicAdd(deg + d, 1);
    if (pos < CAP) {
        bucket[(size_t)d * CAP + pos] = s;
    } else {
        int o = atomicAdd(ovf_cnt, 1);
        if (o < OVF_CAP) { ovf[2 * o] = s; ovf[2 * o + 1] = d; }
    }
}

// ---------------------------------------------------------------------------
// Kernel 3: gather-sum + mean, writes agg in MFMA-fragment order.
// Batch-8 predicated load issue: all <=8 loads of a batch are independent
// and in flight before the first use -> one latency exposure for 74% of
// nodes (P[deg<=8] under Poisson(6)) instead of batch(4)+serial-tail.
// ---------------------------------------------------------------------------
__global__ __launch_bounds__(256) void gather_kernel(
    const unsigned short* __restrict__ xsb,  // [N, 128] bf16 linear
    const int*   __restrict__ deg,      // [N]
    const int*   __restrict__ bucket,   // [N*CAP]
    const int*   __restrict__ ovf_cnt,  // [1]
    const int*   __restrict__ ovf,      // [OVF_CAP*2]
    unsigned int* __restrict__ aggsw)   // fragment-order bf16 mean (dwords)
{
    int node = blockIdx.x * 4 + (threadIdx.x >> 6);
    if (node >= N_NODES) return;
    int lane = threadIdx.x & 63;

    int dtot = deg[node];
    int n = (dtot < CAP) ? dtot : CAP;

    int idx = bucket[(size_t)node * CAP + (lane & 31)];

    float ax = 0.f, ay = 0.f;
    for (int base = 0; base < n; base += 8) {
        unsigned int u[8];
        #pragma unroll
        for (int j = 0; j < 8; ++j) {
            if (base + j < n) {   // wave-uniform predicate; loads independent
                int s = __shfl(idx, base + j);
                u[j] = ((const unsigned int*)(xsb + (size_t)s * D_SRC))[lane];
            } else {
                u[j] = 0;         // bf_lo/bf_hi(0) == 0.f
            }
        }
        #pragma unroll
        for (int j = 0; j < 8; ++j) {
            ax += bf_lo(u[j]);
            ay += bf_hi(u[j]);
        }
    }

    if (dtot > CAP) {   // astronomically rare; correctness fallback
        int oc = *ovf_cnt;
        if (oc > OVF_CAP) oc = OVF_CAP;
        for (int o = 0; o < oc; ++o) {
            if (ovf[2 * o + 1] == node) {
                int s0 = ovf[2 * o];
                unsigned int u0 = ((const unsigned int*)(xsb + (size_t)s0 * D_SRC))[lane];
                ax += bf_lo(u0);
                ay += bf_hi(u0);
            }
        }
    }

    float inv = 1.0f / (float)((dtot > 1) ? dtot : 1);
    unsigned int packed = (unsigned int)f2bf(ax * inv)
                        | ((unsigned int)f2bf(ay * inv) << 16);
    size_t dw = ((size_t)(node >> 4) * 4 + (lane >> 4)) * 256
              + (size_t)((node & 15) + 16 * ((lane >> 2) & 3)) * 4 + (lane & 3);
    aggsw[dw] = packed;
}

// ---------------------------------------------------------------------------
// Kernel 4: MFMA GEMM, operands pre-swizzled to fragment order; register
// double-buffered main loop; wave-private LDS epilogue; nontemporal out
// stores (out is written once, never re-read -> skip L2 write-allocate).
// ---------------------------------------------------------------------------
__global__ __launch_bounds__(256) void mfma_gemm_kernel(
    const short8* __restrict__ xdsw,   // [N/16][4][64] granules
    const short8* __restrict__ aggsw,  // [N/16][4][64] granules
    const short8* __restrict__ wsw,    // [16][8][64] granules
    const float* __restrict__ bias,    // [256]
    float*       __restrict__ out)     // [N, 256] fp32
{
    __shared__ float eps[4][16][68];   // [wave][row][col64 + pad4]

    int wave = threadIdx.x >> 6;  // column block n0 = wave*64
    int lane = threadIdx.x & 63;
    int lrow = lane & 15;
    int kq   = lane >> 4;
    int mb   = blockIdx.x;        // 64-row tile
    int m0   = mb * 64;
    int n0   = wave * 64;

    // validity is uniform per 16-row fragment (N_NODES % 16 == 0)
    bool mok[4];
    #pragma unroll
    for (int mf = 0; mf < 4; ++mf) mok[mf] = (m0 + mf * 16) < N_NODES;

    const short8* Ax = xdsw  + (size_t)mb * 1024 + lane;   // + mf*256 + kc*64
    const short8* Ag = aggsw + (size_t)mb * 1024 + lane;   // + mf*256 + kc'*64
    const short8* Bw = wsw   + (size_t)wave * 2048 + lane; // + nf*512 + kc*64

    float4v acc[4][4];
    #pragma unroll
    for (int i = 0; i < 4; ++i)
        #pragma unroll
        for (int j = 0; j < 4; ++j)
            acc[i][j] = (float4v){0.f, 0.f, 0.f, 0.f};

    const short8 zfrag = (short8){0,0,0,0,0,0,0,0};
    short8 a[2][4], b[2][4];

    #pragma unroll
    for (int mf = 0; mf < 4; ++mf)
        a[0][mf] = mok[mf] ? Ax[mf * 256] : zfrag;
    #pragma unroll
    for (int nf = 0; nf < 4; ++nf)
        b[0][nf] = Bw[nf * 512];

    #pragma unroll
    for (int kc = 0; kc < 8; ++kc) {
        const int cur = kc & 1, nxt = cur ^ 1;
        if (kc < 7) {
            const int k1 = kc + 1;
            const short8* A = (k1 < 4) ? Ax : Ag;
            const int kk = (k1 < 4) ? k1 : (k1 - 4);
            #pragma unroll
            for (int mf = 0; mf < 4; ++mf)
                a[nxt][mf] = mok[mf] ? A[mf * 256 + kk * 64] : zfrag;
            #pragma unroll
            for (int nf = 0; nf < 4; ++nf)
                b[nxt][nf] = Bw[nf * 512 + k1 * 64];
        }
        #pragma unroll
        for (int mf = 0; mf < 4; ++mf)
            #pragma unroll
            for (int nf = 0; nf < 4; ++nf)
                acc[mf][nf] = __builtin_amdgcn_mfma_f32_16x16x32_bf16(
                    a[cur][mf], b[cur][nf], acc[mf][nf], 0, 0, 0);
    }

    // ---- epilogue: bias+relu, wave-private LDS bounce, 256B nt stores ----
    float bv[4];
    #pragma unroll
    for (int nf = 0; nf < 4; ++nf)
        bv[nf] = bias[n0 + nf * 16 + lrow];

    int srow   = lane >> 4;     // 0..3
    int schunk = lane & 15;     // 16B units across 64 cols

    #pragma unroll
    for (int mf = 0; mf < 4; ++mf) {
        if (!mok[mf]) continue;   // block-uniform
        #pragma unroll
        for (int nf = 0; nf < 4; ++nf)
            #pragma unroll
            for (int r = 0; r < 4; ++r)
                eps[wave][kq * 4 + r][nf * 16 + lrow] =
                    fmaxf(acc[mf][nf][r] + bv[nf], 0.f);
        // wave-private slice: wave-local LDS drain instead of __syncthreads
        asm volatile("s_waitcnt lgkmcnt(0)" ::: "memory");
        #pragma unroll
        for (int c = 0; c < 4; ++c) {
            int row  = c * 4 + srow;
            float4v v = *(const float4v*)&eps[wave][row][schunk * 4];
            int grow = m0 + mf * 16 + row;
            __builtin_nontemporal_store(v,
                (float4v*)(out + (size_t)grow * D_OUT + n0 + schunk * 4));
        }
        asm volatile("s_waitcnt lgkmcnt(0)" ::: "memory");
    }
}

extern "C" void kernel_launch(void* const* d_in, const int* in_sizes, int n_in,
                              void* d_out, int out_size, void* d_ws, size_t ws_size,
                              hipStream_t stream) {
    const float* x_src = (const float*)d_in[0];
    const float* x_dst = (const float*)d_in[1];
    const int*   ei    = (const int*)d_in[2];
    const float* W     = (const float*)d_in[3];
    const float* bias  = (const float*)d_in[4];
    float* out = (float*)d_out;

    int n_edges = in_sizes[2] / 2;

    // workspace layout (ws):
    //   deg    : N_NODES int           (zeroed by prep)
    //   ovf_cnt: 4 int                 (zeroed by prep)
    //   ovf    : OVF_CAP*2 int
    //   wsw    : 256*256 ushort  (bf16 W, fragment order)
    //   aggsw  : N/16*4*64*8 ushort (bf16 agg, fragment order)
    //   xdsw   : N/16*4*64*8 ushort (bf16 x_dst, fragment order)
    int* deg     = (int*)d_ws;
    int* ovf_cnt = deg + N_NODES;
    int* ovf     = ovf_cnt + 4;
    unsigned short* wsw   = (unsigned short*)(ovf + OVF_CAP * 2);
    unsigned short* aggsw = wsw + (size_t)D_OUT * K_DIM;
    unsigned short* xdsw  = aggsw + (size_t)(N_NODES / 16) * 4 * 64 * 8;

    // d_out doubles as stream-ordered scratch for buffers dead before GEMM:
    //   bucket : N_NODES*CAP int   at offset 0        (12.8 MB)
    //   xsb    : N_NODES*128 ushort at 12.8 MB        (25.6 MB)
    int* bucket = (int*)d_out;
    unsigned short* xsb = (unsigned short*)(bucket + (size_t)N_NODES * CAP);

    prep_kernel<<<PREP_BLOCKS, 256, 0, stream>>>(
        x_src, x_dst, W, xsb, xdsw, wsw, deg);

    bucket_kernel<<<(n_edges + 255) / 256, 256, 0, stream>>>(
        ei, deg, ovf_cnt, ovf, bucket, n_edges);

    gather_kernel<<<(N_NODES + 3) / 4, 256, 0, stream>>>(
        xsb, deg, bucket, ovf_cnt, ovf, (unsigned int*)aggsw);

    mfma_gemm_kernel<<<(N_NODES + 63) / 64, 256, 0, stream>>>(
        (const short8*)xdsw, (const short8*)aggsw, (const short8*)wsw, bias, out);
}

// Round 4
// 289.822 us; speedup vs baseline: 1.0994x; 1.0994x over previous
//
#include <hip/hip_runtime.h>

#define N_NODES 100000
#define D_SRC 128
#define D_OUT 256
#define K_DIM 256   // D_DST + D_SRC
#define CAP 32      // bucket capacity per node (Poisson(6): P(deg>32) ~ 1e-15)
#define OVF_CAP 2048

typedef __attribute__((ext_vector_type(8))) short short8;
typedef __attribute__((ext_vector_type(4))) float float4v;
typedef __attribute__((ext_vector_type(4))) unsigned int uint4v;

__device__ inline unsigned short f2bf(float f) {
    unsigned int u = __float_as_uint(f);
    u += 0x7FFF + ((u >> 16) & 1);   // round-to-nearest-even
    return (unsigned short)(u >> 16);
}
__device__ inline float bf_lo(unsigned int u) { return __uint_as_float(u << 16); }
__device__ inline float bf_hi(unsigned int u) { return __uint_as_float(u & 0xFFFF0000u); }

// ---------------------------------------------------------------------------
// Kernel 1 (fused prep): one launch does all independent elementwise work:
//   blocks [0, 12500)      : x_src fp32 -> bf16 linear pack (xsb)
//   blocks [12500, 18750)  : x_dst fp32 -> bf16 MFMA-fragment pack (xdsw)
//   blocks [18750, 18782)  : W fp32 -> bf16 MFMA-fragment pack (wsw)
//   blocks [18782, 18880)  : zero deg + ovf_cnt (int4 stores)
// ---------------------------------------------------------------------------
#define PREP_SRC_BLOCKS 12500              // N*128/4 float4 / 256
#define PREP_DST_BLOCKS 6250               // N*16 threads / 256
#define PREP_W_BLOCKS   32                 // 256*256/8 / 256
#define PREP_Z_BLOCKS   98                 // ceil((N+4)/4 int4 / 256)
#define PREP_BLOCKS (PREP_SRC_BLOCKS + PREP_DST_BLOCKS + PREP_W_BLOCKS + PREP_Z_BLOCKS)

__global__ __launch_bounds__(256) void prep_kernel(
    const float* __restrict__ x_src,
    const float* __restrict__ x_dst,
    const float* __restrict__ W,
    unsigned short* __restrict__ xsb,
    unsigned short* __restrict__ xdsw,
    unsigned short* __restrict__ wsw,
    int* __restrict__ deg)             // zeroes N_NODES+4 ints (deg + ovf_cnt)
{
    int b = blockIdx.x;
    if (b < PREP_SRC_BLOCKS) {
        int i = b * 256 + threadIdx.x;
        float4 v = ((const float4*)x_src)[i];
        ushort4 o;
        o.x = f2bf(v.x); o.y = f2bf(v.y); o.z = f2bf(v.z); o.w = f2bf(v.w);
        ((ushort4*)xsb)[i] = o;
    } else if (b < PREP_SRC_BLOCKS + PREP_DST_BLOCKS) {
        // granule ((r>>4)*4 + kc)*64 + (r&15) + 16*sub  <- x_dst[r][kc*32+sub*8+j]
        int t = (b - PREP_SRC_BLOCKS) * 256 + threadIdx.x;
        int r = t >> 4;
        int g = t & 15;
        const float4* p = (const float4*)(x_dst + (size_t)r * 128 + g * 8);
        float4 v0 = p[0], v1 = p[1];
        union { unsigned short s[8]; short8 v; } pk;
        pk.s[0] = f2bf(v0.x); pk.s[1] = f2bf(v0.y);
        pk.s[2] = f2bf(v0.z); pk.s[3] = f2bf(v0.w);
        pk.s[4] = f2bf(v1.x); pk.s[5] = f2bf(v1.y);
        pk.s[6] = f2bf(v1.z); pk.s[7] = f2bf(v1.w);
        size_t gr = ((size_t)(r >> 4) * 4 + (g >> 2)) * 64 + (r & 15) + ((g & 3) << 4);
        ((short8*)xdsw)[gr] = pk.v;
    } else if (b < PREP_SRC_BLOCKS + PREP_DST_BLOCKS + PREP_W_BLOCKS) {
        // granule ((r>>4)*8 + kc)*64 + (r&15) + 16*sub  (r = out-row)
        int t = (b - PREP_SRC_BLOCKS - PREP_DST_BLOCKS) * 256 + threadIdx.x;
        int r = t >> 5;
        int g = t & 31;
        const float4* p = (const float4*)(W + (size_t)r * 256 + g * 8);
        float4 v0 = p[0], v1 = p[1];
        union { unsigned short s[8]; short8 v; } pk;
        pk.s[0] = f2bf(v0.x); pk.s[1] = f2bf(v0.y);
        pk.s[2] = f2bf(v0.z); pk.s[3] = f2bf(v0.w);
        pk.s[4] = f2bf(v1.x); pk.s[5] = f2bf(v1.y);
        pk.s[6] = f2bf(v1.z); pk.s[7] = f2bf(v1.w);
        size_t gr = ((size_t)(r >> 4) * 8 + (g >> 2)) * 64 + (r & 15) + ((g & 3) << 4);
        ((short8*)wsw)[gr] = pk.v;
    } else {
        int i = (b - PREP_SRC_BLOCKS - PREP_DST_BLOCKS - PREP_W_BLOCKS) * 256 + threadIdx.x;
        if (i < (N_NODES + 4) / 4)
            ((int4*)deg)[i] = make_int4(0, 0, 0, 0);
    }
}

// ---------------------------------------------------------------------------
// Kernel 2: bucket edges by dst. (unchanged)
// ---------------------------------------------------------------------------
__global__ __launch_bounds__(256) void bucket_kernel(
    const int* __restrict__ ei,     // [2, E]
    int* __restrict__ deg,          // [N] (pre-zeroed)
    int* __restrict__ ovf_cnt,      // [1] (pre-zeroed)
    int* __restrict__ ovf,          // [OVF_CAP*2]
    int* __restrict__ bucket,       // [N*CAP]
    int n_edges)
{
    int e = blockIdx.x * 256 + threadIdx.x;
    if (e >= n_edges) return;
    int s = ei[e];
    int d = ei[n_edges + e];
    int pos = atomicAdd(deg + d, 1);
    if (pos < CAP) {
        bucket[(size_t)d * CAP + pos] = s;
    } else {
        int o = atomicAdd(ovf_cnt, 1);
        if (o < OVF_CAP) { ovf[2 * o] = s; ovf[2 * o + 1] = d; }
    }
}

// ---------------------------------------------------------------------------
// Kernel 3: gather-sum + mean, 4 NODES PER WAVE.
// Lanes: grp = lane>>4 (row-slot / node-group), gcol = lane&15 (16B chunk).
// One dwordx4 load covers 4 rows of a node's bucket per instruction; the
// 4 nodes' batches are double-buffered (issue b+1 before accumulating b),
// so one wave keeps >= 8 x 256B loads in flight across its whole life and
// amortizes the bucket->shfl->gather chain over 4 nodes instead of 1.
// Epilogue: butterfly (xor16, xor32) sums row-groups, cndmask-select by
// grp (static register indexing), one fully-coalesced 1KB wave store.
// ---------------------------------------------------------------------------
#define G_ISSUE(U, V, B)                                                      \
    {                                                                         \
        int r_ = (B) + grp;                                                   \
        { bool v_ = r_ < n0; V[0] = v_; int s_ = __shfl(idx0, r_);            \
          s_ = v_ ? s_ : 0;                                                   \
          U[0] = *(const uint4v*)(xsb + (size_t)s_ * D_SRC + gcol * 8); }     \
        { bool v_ = r_ < n1; V[1] = v_; int s_ = __shfl(idx1, r_);            \
          s_ = v_ ? s_ : 0;                                                   \
          U[1] = *(const uint4v*)(xsb + (size_t)s_ * D_SRC + gcol * 8); }     \
        { bool v_ = r_ < n2; V[2] = v_; int s_ = __shfl(idx2, r_);            \
          s_ = v_ ? s_ : 0;                                                   \
          U[2] = *(const uint4v*)(xsb + (size_t)s_ * D_SRC + gcol * 8); }     \
        { bool v_ = r_ < n3; V[3] = v_; int s_ = __shfl(idx3, r_);            \
          s_ = v_ ? s_ : 0;                                                   \
          U[3] = *(const uint4v*)(xsb + (size_t)s_ * D_SRC + gcol * 8); }     \
    }

#define G_ACC1(ACC, W)                                                       \
    ACC[0] += bf_lo(W[0]); ACC[1] += bf_hi(W[0]);                            \
    ACC[2] += bf_lo(W[1]); ACC[3] += bf_hi(W[1]);                            \
    ACC[4] += bf_lo(W[2]); ACC[5] += bf_hi(W[2]);                            \
    ACC[6] += bf_lo(W[3]); ACC[7] += bf_hi(W[3]);

#define G_ACCUM(U, V)                                                        \
    if (V[0]) { G_ACC1(acc0, U[0]) }                                         \
    if (V[1]) { G_ACC1(acc1, U[1]) }                                         \
    if (V[2]) { G_ACC1(acc2, U[2]) }                                         \
    if (V[3]) { G_ACC1(acc3, U[3]) }

__global__ __launch_bounds__(256) void gather_kernel(
    const unsigned short* __restrict__ xsb,  // [N, 128] bf16 linear
    const int*   __restrict__ deg,      // [N]
    const int*   __restrict__ bucket,   // [N*CAP]
    const int*   __restrict__ ovf_cnt,  // [1]
    const int*   __restrict__ ovf,      // [OVF_CAP*2]
    unsigned int* __restrict__ aggsw)   // fragment-order bf16 mean (dwords)
{
    int wid  = threadIdx.x >> 6;
    int lane = threadIdx.x & 63;
    int nbase = (blockIdx.x * 4 + wid) * 4;   // 16 nodes/block; 6250 blocks exact
    if (nbase >= N_NODES) return;
    int grp  = lane >> 4;                     // 0..3
    int gcol = lane & 15;                     // 16B chunk within row

    // degrees for the 4 nodes (lanes load 4 ints, broadcast via readlane)
    int dl  = deg[nbase + (lane & 3)];
    int dt0 = __shfl(dl, 0), dt1 = __shfl(dl, 1);
    int dt2 = __shfl(dl, 2), dt3 = __shfl(dl, 3);
    int n0 = min(dt0, CAP), n1 = min(dt1, CAP);
    int n2 = min(dt2, CAP), n3 = min(dt3, CAP);

    // bucket rows (4 x 128B, sequential 512B per wave)
    int idx0 = bucket[(size_t)(nbase + 0) * CAP + (lane & 31)];
    int idx1 = bucket[(size_t)(nbase + 1) * CAP + (lane & 31)];
    int idx2 = bucket[(size_t)(nbase + 2) * CAP + (lane & 31)];
    int idx3 = bucket[(size_t)(nbase + 3) * CAP + (lane & 31)];

    float acc0[8] = {0,0,0,0,0,0,0,0}, acc1[8] = {0,0,0,0,0,0,0,0};
    float acc2[8] = {0,0,0,0,0,0,0,0}, acc3[8] = {0,0,0,0,0,0,0,0};

    int maxn = max(max(n0, n1), max(n2, n3));

    uint4v uA[4], uB[4];
    bool   vA[4], vB[4];
    if (maxn > 0) {
        G_ISSUE(uA, vA, 0)
        int b = 0;
        while (true) {
            if (b + 4 < maxn) { G_ISSUE(uB, vB, b + 4) }
            G_ACCUM(uA, vA)
            b += 4;
            if (b >= maxn) break;
            if (b + 4 < maxn) { G_ISSUE(uA, vA, b + 4) }
            G_ACCUM(uB, vB)
            b += 4;
            if (b >= maxn) break;
        }
    }

    // overflow fallback (astronomically rare)
    if ((dt0 > CAP) | (dt1 > CAP) | (dt2 > CAP) | (dt3 > CAP)) {
        int oc = *ovf_cnt;
        if (oc > OVF_CAP) oc = OVF_CAP;
        for (int o = 0; o < oc; ++o) {
            int od  = ovf[2 * o + 1];
            int rel = od - nbase;
            if (rel >= 0 && rel < 4) {
                int s0 = ovf[2 * o];
                uint4v w = *(const uint4v*)(xsb + (size_t)s0 * D_SRC + gcol * 8);
                if (grp == 0) {   // add once; butterfly distributes it
                    if      (rel == 0) { G_ACC1(acc0, w) }
                    else if (rel == 1) { G_ACC1(acc1, w) }
                    else if (rel == 2) { G_ACC1(acc2, w) }
                    else               { G_ACC1(acc3, w) }
                }
            }
        }
    }

    // butterfly-reduce across the 4 row-groups (lanes ^16, ^32)
    #pragma unroll
    for (int k = 0; k < 8; ++k) {
        acc0[k] += __shfl_xor(acc0[k], 16); acc0[k] += __shfl_xor(acc0[k], 32);
        acc1[k] += __shfl_xor(acc1[k], 16); acc1[k] += __shfl_xor(acc1[k], 32);
        acc2[k] += __shfl_xor(acc2[k], 16); acc2[k] += __shfl_xor(acc2[k], 32);
        acc3[k] += __shfl_xor(acc3[k], 16); acc3[k] += __shfl_xor(acc3[k], 32);
    }

    // lane (grp, gcol) stores granule gcol of node nbase+grp (static select)
    int dsel = dt0;
    dsel = (grp == 1) ? dt1 : dsel;
    dsel = (grp == 2) ? dt2 : dsel;
    dsel = (grp == 3) ? dt3 : dsel;
    float inv = 1.0f / (float)((dsel > 1) ? dsel : 1);

    float sum[8];
    #pragma unroll
    for (int k = 0; k < 8; ++k) {
        float v = acc0[k];
        v = (grp == 1) ? acc1[k] : v;
        v = (grp == 2) ? acc2[k] : v;
        v = (grp == 3) ? acc3[k] : v;
        sum[k] = v * inv;
    }

    uint4v o;
    o[0] = (unsigned)f2bf(sum[0]) | ((unsigned)f2bf(sum[1]) << 16);
    o[1] = (unsigned)f2bf(sum[2]) | ((unsigned)f2bf(sum[3]) << 16);
    o[2] = (unsigned)f2bf(sum[4]) | ((unsigned)f2bf(sum[5]) << 16);
    o[3] = (unsigned)f2bf(sum[6]) | ((unsigned)f2bf(sum[7]) << 16);

    int node = nbase + grp;
    size_t gr = ((size_t)(node >> 4) * 4 + (gcol >> 2)) * 64
              + (node & 15) + ((gcol & 3) << 4);
    ((uint4v*)aggsw)[gr] = o;
}

// ---------------------------------------------------------------------------
// Kernel 4: MFMA GEMM (unchanged from round 3).
// ---------------------------------------------------------------------------
__global__ __launch_bounds__(256) void mfma_gemm_kernel(
    const short8* __restrict__ xdsw,   // [N/16][4][64] granules
    const short8* __restrict__ aggsw,  // [N/16][4][64] granules
    const short8* __restrict__ wsw,    // [16][8][64] granules
    const float* __restrict__ bias,    // [256]
    float*       __restrict__ out)     // [N, 256] fp32
{
    __shared__ float eps[4][16][68];   // [wave][row][col64 + pad4]

    int wave = threadIdx.x >> 6;  // column block n0 = wave*64
    int lane = threadIdx.x & 63;
    int lrow = lane & 15;
    int kq   = lane >> 4;
    int mb   = blockIdx.x;        // 64-row tile
    int m0   = mb * 64;
    int n0   = wave * 64;

    bool mok[4];
    #pragma unroll
    for (int mf = 0; mf < 4; ++mf) mok[mf] = (m0 + mf * 16) < N_NODES;

    const short8* Ax = xdsw  + (size_t)mb * 1024 + lane;   // + mf*256 + kc*64
    const short8* Ag = aggsw + (size_t)mb * 1024 + lane;   // + mf*256 + kc'*64
    const short8* Bw = wsw   + (size_t)wave * 2048 + lane; // + nf*512 + kc*64

    float4v acc[4][4];
    #pragma unroll
    for (int i = 0; i < 4; ++i)
        #pragma unroll
        for (int j = 0; j < 4; ++j)
            acc[i][j] = (float4v){0.f, 0.f, 0.f, 0.f};

    const short8 zfrag = (short8){0,0,0,0,0,0,0,0};
    short8 a[2][4], b[2][4];

    #pragma unroll
    for (int mf = 0; mf < 4; ++mf)
        a[0][mf] = mok[mf] ? Ax[mf * 256] : zfrag;
    #pragma unroll
    for (int nf = 0; nf < 4; ++nf)
        b[0][nf] = Bw[nf * 512];

    #pragma unroll
    for (int kc = 0; kc < 8; ++kc) {
        const int cur = kc & 1, nxt = cur ^ 1;
        if (kc < 7) {
            const int k1 = kc + 1;
            const short8* A = (k1 < 4) ? Ax : Ag;
            const int kk = (k1 < 4) ? k1 : (k1 - 4);
            #pragma unroll
            for (int mf = 0; mf < 4; ++mf)
                a[nxt][mf] = mok[mf] ? A[mf * 256 + kk * 64] : zfrag;
            #pragma unroll
            for (int nf = 0; nf < 4; ++nf)
                b[nxt][nf] = Bw[nf * 512 + k1 * 64];
        }
        #pragma unroll
        for (int mf = 0; mf < 4; ++mf)
            #pragma unroll
            for (int nf = 0; nf < 4; ++nf)
                acc[mf][nf] = __builtin_amdgcn_mfma_f32_16x16x32_bf16(
                    a[cur][mf], b[cur][nf], acc[mf][nf], 0, 0, 0);
    }

    // ---- epilogue: bias+relu, wave-private LDS bounce, 256B nt stores ----
    float bv[4];
    #pragma unroll
    for (int nf = 0; nf < 4; ++nf)
        bv[nf] = bias[n0 + nf * 16 + lrow];

    int srow   = lane >> 4;     // 0..3
    int schunk = lane & 15;     // 16B units across 64 cols

    #pragma unroll
    for (int mf = 0; mf < 4; ++mf) {
        if (!mok[mf]) continue;   // block-uniform
        #pragma unroll
        for (int nf = 0; nf < 4; ++nf)
            #pragma unroll
            for (int r = 0; r < 4; ++r)
                eps[wave][kq * 4 + r][nf * 16 + lrow] =
                    fmaxf(acc[mf][nf][r] + bv[nf], 0.f);
        asm volatile("s_waitcnt lgkmcnt(0)" ::: "memory");
        #pragma unroll
        for (int c = 0; c < 4; ++c) {
            int row  = c * 4 + srow;
            float4v v = *(const float4v*)&eps[wave][row][schunk * 4];
            int grow = m0 + mf * 16 + row;
            __builtin_nontemporal_store(v,
                (float4v*)(out + (size_t)grow * D_OUT + n0 + schunk * 4));
        }
        asm volatile("s_waitcnt lgkmcnt(0)" ::: "memory");
    }
}

extern "C" void kernel_launch(void* const* d_in, const int* in_sizes, int n_in,
                              void* d_out, int out_size, void* d_ws, size_t ws_size,
                              hipStream_t stream) {
    const float* x_src = (const float*)d_in[0];
    const float* x_dst = (const float*)d_in[1];
    const int*   ei    = (const int*)d_in[2];
    const float* W     = (const float*)d_in[3];
    const float* bias  = (const float*)d_in[4];
    float* out = (float*)d_out;

    int n_edges = in_sizes[2] / 2;

    // workspace layout (ws):
    //   deg    : N_NODES int           (zeroed by prep)
    //   ovf_cnt: 4 int                 (zeroed by prep)
    //   ovf    : OVF_CAP*2 int
    //   wsw    : 256*256 ushort  (bf16 W, fragment order)
    //   aggsw  : N/16*4*64*8 ushort (bf16 agg, fragment order)
    //   xdsw   : N/16*4*64*8 ushort (bf16 x_dst, fragment order)
    int* deg     = (int*)d_ws;
    int* ovf_cnt = deg + N_NODES;
    int* ovf     = ovf_cnt + 4;
    unsigned short* wsw   = (unsigned short*)(ovf + OVF_CAP * 2);
    unsigned short* aggsw = wsw + (size_t)D_OUT * K_DIM;
    unsigned short* xdsw  = aggsw + (size_t)(N_NODES / 16) * 4 * 64 * 8;

    // d_out doubles as stream-ordered scratch for buffers dead before GEMM:
    //   bucket : N_NODES*CAP int   at offset 0        (12.8 MB)
    //   xsb    : N_NODES*128 ushort at 12.8 MB        (25.6 MB)
    int* bucket = (int*)d_out;
    unsigned short* xsb = (unsigned short*)(bucket + (size_t)N_NODES * CAP);

    prep_kernel<<<PREP_BLOCKS, 256, 0, stream>>>(
        x_src, x_dst, W, xsb, xdsw, wsw, deg);

    bucket_kernel<<<(n_edges + 255) / 256, 256, 0, stream>>>(
        ei, deg, ovf_cnt, ovf, bucket, n_edges);

    gather_kernel<<<(N_NODES + 15) / 16, 256, 0, stream>>>(
        xsb, deg, bucket, ovf_cnt, ovf, (unsigned int*)aggsw);

    mfma_gemm_kernel<<<(N_NODES + 63) / 64, 256, 0, stream>>>(
        (const short8*)xdsw, (const short8*)aggsw, (const short8*)wsw, bias, out);
}